// Round 9
// baseline (29.110 us; speedup 1.0000x reference)
//
#include <hip/hip_runtime.h>

// Problem constants (match reference)
#define BB 32
#define DD 32
#define HH 256
#define WW 256
#define KK 512

typedef __attribute__((ext_vector_type(8))) short bf16x8;
typedef __attribute__((ext_vector_type(4))) float f32x4;

// ws layout (bytes): [0,1MB) bf16-hi ushort[16384*32]; [1MB,2MB) bf16-lo; [2MB,+64KB) ssq f32
#define LO_OFF  (1u << 20)
#define SSQ_OFF (2u << 20)

// ---------------------------------------------------------------------------
// Kernel A: gather with 4 independent scattered loads per thread (ILP).
// Block covers 4 consecutive 256-gid slices; within a slice the (col,d)
// mapping, ssq shuffle, and coalesced stores are identical to the validated
// 1-load/thread version. All 4 ebd addresses are computed up front so the
// loads pipeline (single vmcnt drain instead of 4 serial latencies).
// ---------------------------------------------------------------------------
__global__ __launch_bounds__(256) void tagloss_gather(
    const float* __restrict__ ebd, const int* __restrict__ kpts,
    char* __restrict__ ws, float* __restrict__ out) {
  const int tid = threadIdx.x;
  const int g0 = blockIdx.x * 1024 + tid;     // slice stride 256
  if (g0 == 0) out[0] = 0.f;

  float v[4];
#pragma unroll
  for (int i = 0; i < 4; ++i) {
    int gid = g0 + i * 256;
    int col = gid >> 5;                       // 0 .. BB*KK-1
    int d   = gid & 31;
    int b   = col >> 9;
    int y = kpts[col * 2 + 0];
    int x = kpts[col * 2 + 1];
    v[i] = ebd[((size_t)(b * DD + d)) * (HH * WW) + (size_t)y * WW + x];
  }

#pragma unroll
  for (int i = 0; i < 4; ++i) {
    int gid = g0 + i * 256;
    int col = gid >> 5;
    int d   = gid & 31;

    unsigned u  = __float_as_uint(v[i]);
    unsigned rn = u + 0x7FFFu + ((u >> 16) & 1u);      // RN-to-bf16 (ties-even)
    float hif = __uint_as_float(rn & 0xFFFF0000u);
    float lof = v[i] - hif;                             // exact
    unsigned ul = __float_as_uint(lof);
    unsigned rl = ul + 0x7FFFu + ((ul >> 16) & 1u);

    ((ushort*)ws)[col * DD + d]            = (ushort)(rn >> 16);
    ((ushort*)(ws + LO_OFF))[col * DD + d] = (ushort)(rl >> 16);

    float s = v[i] * v[i];
#pragma unroll
    for (int m = 16; m > 0; m >>= 1) s += __shfl_xor(s, m);
    if (d == 0) ((float*)(ws + SSQ_OFF))[col] = s;
  }
}

// ---------------------------------------------------------------------------
// Kernel B: validated R7 pairs. Staging via global_load_lds width=16 with
// pre-swizzled global source (LDS dest linear; phys layout = logical chunk
// pc ^ ((col>>1)&3), reads unchanged). Balanced triangle k-tile pair
// {p, 31-p} (33 jobs, off-diag weight 2), 3 chained mfma_f32_16x16x32_bf16
// per job, sigmoid-MSE epilogue, wave reduce, 1 atomic/block.
// ---------------------------------------------------------------------------
__global__ __launch_bounds__(256, 2) void tagloss_pairs(
    const char* __restrict__ ws, const int* __restrict__ tags,
    float* __restrict__ out) {
  __shared__ __align__(16) char P[65536];   // [plane 32KB][col*64 + swz_chunk*16]
  __shared__ float ssqL[KK];
  __shared__ int   tagL[KK];
  __shared__ float red[4];

  const int tid = threadIdx.x;
  const int b = blockIdx.y;
  const int p = blockIdx.x;                 // 0..15 -> k-tile pair {p, 31-p}

  // ---- stage: 4096 16B chunks via async global->LDS DMA ----
  const char* wsb = ws + (size_t)b * 32768;
#pragma unroll
  for (int i = 0; i < 16; ++i) {
    int j = tid + i * 256;            // 0..4095 (phys slot, linear in LDS)
    int plane = j >> 11;              // 0 = hi, 1 = lo
    int col = (j >> 2) & 511;
    int pc = j & 3;
    const char* gsrc = wsb + (size_t)plane * LO_OFF + col * 64 +
                       ((pc ^ ((col >> 1) & 3)) * 16);
    char* ldst = P + ((i * 256 + (tid & ~63)) * 16);
    __builtin_amdgcn_global_load_lds(
        (const __attribute__((address_space(1))) void*)gsrc,
        (__attribute__((address_space(3))) void*)ldst, 16, 0, 0);
  }
  ssqL[tid]       = ((const float*)(ws + SSQ_OFF))[b * KK + tid];
  ssqL[tid + 256] = ((const float*)(ws + SSQ_OFF))[b * KK + tid + 256];
  tagL[tid]       = tags[b * KK + tid];
  tagL[tid + 256] = tags[b * KK + tid + 256];
  __syncthreads();   // drains vmcnt (global_load_lds) + lgkm

  // ---- compute ----
  const int w = tid >> 6, lane = tid & 63;
  const int lx = lane & 15, dchunk = lane >> 4;

  const int i0 = p, i1 = 31 - p;            // the two k-tiles (16 rows each)
  const int lim = 32 - i0;                  // job count of row i0

  const int colA0 = i0 * 16 + lx;
  const int colA1 = i1 * 16 + lx;
  const int swzA0 = ((dchunk ^ ((colA0 >> 1) & 3)) * 16);
  const int swzA1 = ((dchunk ^ ((colA1 >> 1) & 3)) * 16);
  bf16x8 a0hi = *(const bf16x8*)(P + colA0 * 64 + swzA0);
  bf16x8 a0lo = *(const bf16x8*)(P + 32768 + colA0 * 64 + swzA0);
  bf16x8 a1hi = *(const bf16x8*)(P + colA1 * 64 + swzA1);
  bf16x8 a1lo = *(const bf16x8*)(P + 32768 + colA1 * 64 + swzA1);

  const int krow0 = i0 * 16 + dchunk * 4;
  const int krow1 = i1 * 16 + dchunk * 4;
  float ssqk0[4], ssqk1[4];
  int   tagk0[4], tagk1[4];
#pragma unroll
  for (int r = 0; r < 4; ++r) {
    ssqk0[r] = ssqL[krow0 + r]; tagk0[r] = tagL[krow0 + r];
    ssqk1[r] = ssqL[krow1 + r]; tagk1[r] = tagL[krow1 + r];
  }

  float loss = 0.f;

#define JOB(AHI, ALO, SSQK, TAGK, KT, JT)                                      \
  {                                                                            \
    const int colB = (JT) * 16 + lx;                                           \
    const int swzB = ((dchunk ^ ((colB >> 1) & 3)) * 16);                      \
    bf16x8 bhi = *(const bf16x8*)(P + colB * 64 + swzB);                       \
    bf16x8 blo = *(const bf16x8*)(P + 32768 + colB * 64 + swzB);               \
    f32x4 acc = {0.f, 0.f, 0.f, 0.f};                                          \
    acc = __builtin_amdgcn_mfma_f32_16x16x32_bf16(ALO, bhi, acc, 0, 0, 0);     \
    acc = __builtin_amdgcn_mfma_f32_16x16x32_bf16(AHI, blo, acc, 0, 0, 0);     \
    acc = __builtin_amdgcn_mfma_f32_16x16x32_bf16(AHI, bhi, acc, 0, 0, 0);     \
    float ssql = ssqL[colB];                                                   \
    int   tagl = tagL[colB];                                                   \
    float jobLoss = 0.f;                                                       \
    _Pragma("unroll")                                                          \
    for (int r = 0; r < 4; ++r) {                                              \
      float expo = (SSQK[r] + ssql - 2.f * acc[r]) * 0.03125f;                 \
      float ps = 2.f * __builtin_amdgcn_rcpf(1.f + __expf(expo));              \
      float t = (TAGK[r] == tagl) ? 1.f : 0.f;                                 \
      float df = t - ps;                                                       \
      jobLoss = fmaf(df, df, jobLoss);                                         \
    }                                                                          \
    float wtf = ((KT) == (JT)) ? 1.f : 2.f;                                    \
    loss = fmaf(jobLoss, wtf, loss);                                           \
  }

  for (int t = w; t < lim; t += 4) JOB(a0hi, a0lo, ssqk0, tagk0, i0, i0 + t);
  {
    int m0 = (lim > w) ? ((lim - w + 3) >> 2) : 0;
    for (int t = w + 4 * m0; t < 33; t += 4)
      JOB(a1hi, a1lo, ssqk1, tagk1, i1, i1 + (t - lim));
  }
#undef JOB

  // ---- reduce ----
#pragma unroll
  for (int off = 32; off > 0; off >>= 1) loss += __shfl_down(loss, off);
  if (lane == 0) red[w] = loss;
  __syncthreads();
  if (tid == 0)
    atomicAdd(out, (red[0] + red[1] + red[2] + red[3]) * (1.f / 8388608.f));
}

extern "C" void kernel_launch(void* const* d_in, const int* in_sizes, int n_in,
                              void* d_out, int out_size, void* d_ws, size_t ws_size,
                              hipStream_t stream) {
  const float* ebd  = (const float*)d_in[0];
  const int*   kpts = (const int*)d_in[1];
  const int*   tags = (const int*)d_in[2];
  float* out = (float*)d_out;

  tagloss_gather<<<(BB * KK * DD) / 1024, 256, 0, stream>>>(ebd, kpts, (char*)d_ws, out);
  tagloss_pairs<<<dim3(16, BB), 256, 0, stream>>>((const char*)d_ws, tags, out);
}

// Round 10
// 26.596 us; speedup vs baseline: 1.0945x; 1.0945x over previous
//
#include <hip/hip_runtime.h>

// Problem constants (match reference)
#define BB 32
#define DD 32
#define HH 256
#define WW 256
#define KK 512

typedef __attribute__((ext_vector_type(8))) short bf16x8;
typedef __attribute__((ext_vector_type(4))) float f32x4;

// ws layout (bytes): [0,1MB) bf16 ushort[16384*32]; [1MB,+64KB) ssq f32 (exact)
#define SSQ_OFF (1u << 20)

// ---------------------------------------------------------------------------
// Kernel A: gather pred[b][k][d] -> RN-bf16 (hi only; error analysis shows
// the compensated lo plane is unnecessary: random unbiased ~2e-4/pair errors
// cancel over the 8.4M-pair mean, ~1e-7 systematic vs 1.8e-3 threshold).
// ssq from exact f32 v. One thread per (col,d); thread 0 zeroes out[0].
// ---------------------------------------------------------------------------
__global__ __launch_bounds__(256) void tagloss_gather(
    const float* __restrict__ ebd, const int* __restrict__ kpts,
    char* __restrict__ ws, float* __restrict__ out) {
  int gid = blockIdx.x * 256 + threadIdx.x;   // 0 .. BB*KK*DD-1
  if (gid == 0) out[0] = 0.f;
  int col = gid >> 5;                         // 0 .. BB*KK-1
  int d   = gid & 31;
  int b   = col >> 9;

  int y = kpts[col * 2 + 0];
  int x = kpts[col * 2 + 1];
  float v = ebd[((size_t)(b * DD + d)) * (HH * WW) + (size_t)y * WW + x];

  unsigned u  = __float_as_uint(v);
  unsigned rn = u + 0x7FFFu + ((u >> 16) & 1u);        // RN-to-bf16 (ties-even)
  ((ushort*)ws)[col * DD + d] = (ushort)(rn >> 16);

  float s = v * v;
#pragma unroll
  for (int m = 16; m > 0; m >>= 1) s += __shfl_xor(s, m);
  if (d == 0) ((float*)(ws + SSQ_OFF))[col] = s;
}

// ---------------------------------------------------------------------------
// Kernel B: R7 pairs structure, hi-plane only (1 MFMA per job), LDS 37KB ->
// 4 blocks/CU. Staging via global_load_lds width=16, pre-swizzled global
// source (LDS dest linear; phys layout = logical chunk pc ^ ((col>>1)&3)).
// Balanced triangle k-tile pair {p, 31-p} (33 jobs, off-diag weight 2),
// sigmoid-MSE epilogue with exact-f32 ssq, wave reduce, 1 atomic/block.
// ---------------------------------------------------------------------------
__global__ __launch_bounds__(256, 4) void tagloss_pairs(
    const char* __restrict__ ws, const int* __restrict__ tags,
    float* __restrict__ out) {
  __shared__ __align__(16) char P[32768];   // [col*64 + swz_chunk*16]
  __shared__ float ssqL[KK];
  __shared__ int   tagL[KK];
  __shared__ float red[4];

  const int tid = threadIdx.x;
  const int b = blockIdx.y;
  const int p = blockIdx.x;                 // 0..15 -> k-tile pair {p, 31-p}

  // ---- stage: 2048 16B chunks via async global->LDS DMA ----
  const char* wsb = ws + (size_t)b * 32768;
#pragma unroll
  for (int i = 0; i < 8; ++i) {
    int j = tid + i * 256;            // 0..2047 (phys slot, linear in LDS)
    int col = j >> 2;
    int pc = j & 3;
    const char* gsrc = wsb + col * 64 + ((pc ^ ((col >> 1) & 3)) * 16);
    char* ldst = P + ((i * 256 + (tid & ~63)) * 16);
    __builtin_amdgcn_global_load_lds(
        (const __attribute__((address_space(1))) void*)gsrc,
        (__attribute__((address_space(3))) void*)ldst, 16, 0, 0);
  }
  ssqL[tid]       = ((const float*)(ws + SSQ_OFF))[b * KK + tid];
  ssqL[tid + 256] = ((const float*)(ws + SSQ_OFF))[b * KK + tid + 256];
  tagL[tid]       = tags[b * KK + tid];
  tagL[tid + 256] = tags[b * KK + tid + 256];
  __syncthreads();   // drains vmcnt (global_load_lds) + lgkm

  // ---- compute ----
  const int w = tid >> 6, lane = tid & 63;
  const int lx = lane & 15, dchunk = lane >> 4;

  const int i0 = p, i1 = 31 - p;            // the two k-tiles (16 rows each)
  const int lim = 32 - i0;                  // job count of row i0

  const int colA0 = i0 * 16 + lx;
  const int colA1 = i1 * 16 + lx;
  bf16x8 a0 = *(const bf16x8*)(P + colA0 * 64 + ((dchunk ^ ((colA0 >> 1) & 3)) * 16));
  bf16x8 a1 = *(const bf16x8*)(P + colA1 * 64 + ((dchunk ^ ((colA1 >> 1) & 3)) * 16));

  const int krow0 = i0 * 16 + dchunk * 4;
  const int krow1 = i1 * 16 + dchunk * 4;
  float ssqk0[4], ssqk1[4];
  int   tagk0[4], tagk1[4];
#pragma unroll
  for (int r = 0; r < 4; ++r) {
    ssqk0[r] = ssqL[krow0 + r]; tagk0[r] = tagL[krow0 + r];
    ssqk1[r] = ssqL[krow1 + r]; tagk1[r] = tagL[krow1 + r];
  }

  float loss = 0.f;

#define JOB(AREG, SSQK, TAGK, KT, JT)                                          \
  {                                                                            \
    const int colB = (JT) * 16 + lx;                                           \
    bf16x8 bb = *(const bf16x8*)(P + colB * 64 +                               \
                                 ((dchunk ^ ((colB >> 1) & 3)) * 16));         \
    f32x4 acc = {0.f, 0.f, 0.f, 0.f};                                          \
    acc = __builtin_amdgcn_mfma_f32_16x16x32_bf16(AREG, bb, acc, 0, 0, 0);     \
    float ssql = ssqL[colB];                                                   \
    int   tagl = tagL[colB];                                                   \
    float jobLoss = 0.f;                                                       \
    _Pragma("unroll")                                                          \
    for (int r = 0; r < 4; ++r) {                                              \
      float expo = (SSQK[r] + ssql - 2.f * acc[r]) * 0.03125f;                 \
      float ps = 2.f * __builtin_amdgcn_rcpf(1.f + __expf(expo));              \
      float t = (TAGK[r] == tagl) ? 1.f : 0.f;                                 \
      float df = t - ps;                                                       \
      jobLoss = fmaf(df, df, jobLoss);                                         \
    }                                                                          \
    float wtf = ((KT) == (JT)) ? 1.f : 2.f;                                    \
    loss = fmaf(jobLoss, wtf, loss);                                           \
  }

  // row i0: jobs t = w + 4m < lim, j-tile = i0 + t
  for (int t = w; t < lim; t += 4) JOB(a0, ssqk0, tagk0, i0, i0 + t);
  // row i1: jobs t in [lim, 33), j-tile = i1 + (t - lim)
  {
    int m0 = (lim > w) ? ((lim - w + 3) >> 2) : 0;
    for (int t = w + 4 * m0; t < 33; t += 4)
      JOB(a1, ssqk1, tagk1, i1, i1 + (t - lim));
  }
#undef JOB

  // ---- reduce ----
#pragma unroll
  for (int off = 32; off > 0; off >>= 1) loss += __shfl_down(loss, off);
  if (lane == 0) red[w] = loss;
  __syncthreads();
  if (tid == 0)
    atomicAdd(out, (red[0] + red[1] + red[2] + red[3]) * (1.f / 8388608.f));
}

extern "C" void kernel_launch(void* const* d_in, const int* in_sizes, int n_in,
                              void* d_out, int out_size, void* d_ws, size_t ws_size,
                              hipStream_t stream) {
  const float* ebd  = (const float*)d_in[0];
  const int*   kpts = (const int*)d_in[1];
  const int*   tags = (const int*)d_in[2];
  float* out = (float*)d_out;

  tagloss_gather<<<(BB * KK * DD) / 256, 256, 0, stream>>>(ebd, kpts, (char*)d_ws, out);
  tagloss_pairs<<<dim3(16, BB), 256, 0, stream>>>((const char*)d_ws, tags, out);
}